// Round 1
// baseline (218.152 us; speedup 1.0000x reference)
//
#include <hip/hip_runtime.h>
#include <hip/hip_bf16.h>
#include <stdint.h>

// ScaledDotProductAttention S=4096 D=1024 fp32.
// R12: all three GEMMs moved from the 128^2/4-wave/2-barrier structure (m97-class,
// measured 670 TF, MfmaUtil 26%) to the 256^2/8-wave/4-phase counted-vmcnt schedule
// (m201-class). Key levers: (T3/T4) quarter-tile staging with vmcnt(6) -- loads stay
// in flight across barriers, never drained to 0 in the main loop; (T5) setprio(1)
// around each 16-MFMA cluster; proven conflict-free XOR chunk swizzle retained.
// Region-retire protocol (race-free by construction):
//   phase 1 reads A[im0-3] both k-halves + B k-half0 ; stages tile T+1 {Aq1,Aq3}->other buf
//   phase 2 reads A[im4-7] k0 + B k1              ; stages tile T+2 {Aq0,Aq2}->cur buf
//   phase 3 reads A[im4-7] k1                     ; stages tile T+2 {Bq0,Bq1}->cur buf
//   phase 4 (no reads)                            ; stages tile T+2 {Bq2,Bq3}; vmcnt(6)
// Every staged region's ds_reads were drained by the previous phase's lgkmcnt(0)
// before its end-barrier, so the DMA can land any time. vmcnt(6) at phase 4 = 3
// quarter-pairs (6 loads) in flight; guarantees tile T+1 (last pair staged at this
// block's phase 1) fully landed before block T+1 reads it.

typedef __bf16 bf16_t;
typedef __bf16 bf16x4 __attribute__((ext_vector_type(4)));
typedef __bf16 bf16x8 __attribute__((ext_vector_type(8)));
typedef float f32x4 __attribute__((ext_vector_type(4)));

#define AS1 __attribute__((address_space(1)))
#define AS3 __attribute__((address_space(3)))

__device__ __forceinline__ void async_ld16(const void* g, void* l) {
  // global -> LDS DMA, 16B/lane; LDS dest is wave-uniform base + lane*16 by HW rule.
  __builtin_amdgcn_global_load_lds((AS1 void*)g, (AS3 void*)l, 16, 0, 0);
}

#define SBAR() __builtin_amdgcn_sched_barrier(0)
#define BARRIER()                 \
  do {                            \
    SBAR();                       \
    __builtin_amdgcn_s_barrier(); \
    SBAR();                       \
  } while (0)
#define LGKM0()                                         \
  do {                                                  \
    asm volatile("s_waitcnt lgkmcnt(0)" ::: "memory");  \
    SBAR();                                             \
  } while (0)

// 256x256 tile, BK=64, 8 waves (2M x 4N), per-wave 128x64 output = acc[8][4].
// LDS: 2 bufs x (As 256x64 | Bs 256x64) bf16 = 128 KiB (dynamic).
// MODE 0: QKV epilogue (bias; Q scaled 1/32; V transposed via LDS).
// MODE 1: S epilogue: store exp(acc) bf16 ldc=4096, atomicAdd fp32 row sums.
// MODE 2: O epilogue: zz<3 -> bf16 partial; zz==3 -> fp32 to fout (1/rowsum).
template <int MODE>
__global__ __launch_bounds__(512, 2) void gemm8(
    const bf16_t* __restrict__ A, const bf16_t* __restrict__ B, const int ld,
    const int Klen, bf16_t* __restrict__ o0, bf16_t* __restrict__ o1,
    bf16_t* __restrict__ o2, const float* __restrict__ b0,
    const float* __restrict__ b1, const float* __restrict__ b2,
    float* __restrict__ fout, float* __restrict__ rowsum) {
  extern __shared__ bf16_t smem[];  // 131072 B

  const int t = threadIdx.x;
  const int lane = t & 63;
  const int wave = t >> 6;
  const int wm = wave >> 2;   // 0..1  (M half)
  const int wn = wave & 3;    // 0..3  (N quarter)
  const int q = lane >> 4;
  const int l16 = lane & 15;
  const int xf = l16 & 7;

  // Grid decode: XCD-aware (bid&7 = XCD), bijective per mode.
  int m0, n0, k0 = 0, zz = 0;
  const int bid = blockIdx.x;
  if constexpr (MODE == 0) {
    // 192 blocks = 16m x 12n; per XCD: 4m x 6n region.
    const int x = bid & 7, sl = bid >> 3;  // sl 0..23
    m0 = ((x >> 1) * 4 + (sl & 3)) * 256;
    n0 = ((x & 1) * 6 + (sl >> 2)) * 256;
  } else if constexpr (MODE == 1) {
    // 256 blocks = 16m x 16n; per XCD: 8m x 4n region.
    const int x = bid & 7, sl = bid >> 3;  // sl 0..31
    m0 = ((x >> 2) * 8 + (sl >> 2)) * 256;
    n0 = ((x & 3) * 4 + (sl & 3)) * 256;
  } else {
    // 256 blocks: split-K z = xcd>>1; per XCD: 8m x 4n of one split.
    const int x = bid & 7, sl = bid >> 3;
    zz = x >> 1;
    m0 = ((x & 1) * 8 + (sl >> 2)) * 256;
    n0 = (sl & 3) * 256;
    k0 = zz * Klen;
  }

  // Staging swizzle (R5-proven, conflict-free): GLOBAL chunk = slot ^ (srow&7);
  // LDS stays linear (HW rule). One quarter (64 rows x 64 k) = 1 load/thread.
  const int srow = t >> 3;                      // 0..63
  const int c8s = ((t & 7) ^ (srow & 7)) * 8;
  const bf16_t* Ab = A + (size_t)(m0 + srow) * ld + k0 + c8s;
  const bf16_t* Bb = B + (size_t)(n0 + srow) * ld + k0 + c8s;
  const int tl8 = t * 8;

  // Read-side: frag (im,s) at row wm*128+im*16+l16, LDS slot ((s*4+q)^xf).
  const int aoff = (wm * 128 + l16) * 64;
  const int boff = (wn * 64 + l16) * 64;
  const int c0 = (q ^ xf) * 8;
  const int c1 = ((4 + q) ^ xf) * 8;

  f32x4 acc[8][4];
  const f32x4 zero4 = {0.f, 0.f, 0.f, 0.f};
#pragma unroll
  for (int i = 0; i < 8; ++i)
#pragma unroll
    for (int j = 0; j < 4; ++j) acc[i][j] = zero4;

  const int NT = Klen >> 6;
  bf16_t* buf0 = smem;          // As(16384) | Bs(16384)
  bf16_t* buf1 = smem + 32768;

  // Prologue: tile0 full (8 quarters) -> buf0; tile1 {Aq0,Aq2,Bq0..Bq3} -> buf1.
  async_ld16(Ab, buf0 + tl8);
  async_ld16(Ab + (size_t)128 * ld, buf0 + 128 * 64 + tl8);
  async_ld16(Bb, buf0 + 16384 + tl8);
  async_ld16(Bb + (size_t)64 * ld, buf0 + 16384 + 64 * 64 + tl8);
  async_ld16(Bb + (size_t)128 * ld, buf0 + 16384 + 128 * 64 + tl8);
  async_ld16(Bb + (size_t)192 * ld, buf0 + 16384 + 192 * 64 + tl8);
  async_ld16(Ab + (size_t)64 * ld, buf0 + 64 * 64 + tl8);
  async_ld16(Ab + (size_t)192 * ld, buf0 + 192 * 64 + tl8);
  async_ld16(Ab + 64, buf1 + tl8);
  async_ld16(Ab + (size_t)128 * ld + 64, buf1 + 128 * 64 + tl8);
  async_ld16(Bb + 64, buf1 + 16384 + tl8);
  async_ld16(Bb + (size_t)64 * ld + 64, buf1 + 16384 + 64 * 64 + tl8);
  async_ld16(Bb + (size_t)128 * ld + 64, buf1 + 16384 + 128 * 64 + tl8);
  async_ld16(Bb + (size_t)192 * ld + 64, buf1 + 16384 + 192 * 64 + tl8);
  asm volatile("s_waitcnt vmcnt(6)" ::: "memory");  // tile0 fully landed
  BARRIER();

  for (int T = 0; T < NT; ++T) {
    bf16_t* Ac = (T & 1) ? buf1 : buf0;
    bf16_t* An = (T & 1) ? buf0 : buf1;
    bf16_t* Bc = Ac + 16384;
    const int k1 = (T + 1) << 6;
    const int k2 = (T + 2) << 6;
    const bool s1 = (T + 1) < NT;
    const bool s2 = (T + 2) < NT;

    bf16x8 raA[4][2], raB[4][2], rb[4][2];

    // ---- phase 1: read A im0-3 (both k-halves) + B k0; stage T+1 {Aq1,Aq3}.
#pragma unroll
    for (int im = 0; im < 4; ++im) {
      raA[im][0] = *(const bf16x8*)(Ac + aoff + im * 1024 + c0);
      raA[im][1] = *(const bf16x8*)(Ac + aoff + im * 1024 + c1);
    }
#pragma unroll
    for (int j = 0; j < 4; ++j)
      rb[j][0] = *(const bf16x8*)(Bc + boff + j * 1024 + c0);
    if (s1) {
      async_ld16(Ab + (size_t)64 * ld + k1, An + 64 * 64 + tl8);
      async_ld16(Ab + (size_t)192 * ld + k1, An + 192 * 64 + tl8);
    }
    BARRIER();
    LGKM0();
    __builtin_amdgcn_s_setprio(1);
#pragma unroll
    for (int im = 0; im < 4; ++im)
#pragma unroll
      for (int j = 0; j < 4; ++j)
        acc[im][j] = __builtin_amdgcn_mfma_f32_16x16x32_bf16(
            raA[im][0], rb[j][0], acc[im][j], 0, 0, 0);
    __builtin_amdgcn_s_setprio(0);
    BARRIER();

    // ---- phase 2: read A im4-7 k0 + B k1; stage T+2 {Aq0,Aq2} (retired ph1).
#pragma unroll
    for (int im = 0; im < 4; ++im)
      raB[im][0] = *(const bf16x8*)(Ac + aoff + (im + 4) * 1024 + c0);
#pragma unroll
    for (int j = 0; j < 4; ++j)
      rb[j][1] = *(const bf16x8*)(Bc + boff + j * 1024 + c1);
    if (s2) {
      async_ld16(Ab + k2, Ac + tl8);
      async_ld16(Ab + (size_t)128 * ld + k2, Ac + 128 * 64 + tl8);
    }
    BARRIER();
    LGKM0();
    __builtin_amdgcn_s_setprio(1);
#pragma unroll
    for (int im = 0; im < 4; ++im)
#pragma unroll
      for (int j = 0; j < 4; ++j)
        acc[4 + im][j] = __builtin_amdgcn_mfma_f32_16x16x32_bf16(
            raB[im][0], rb[j][0], acc[4 + im][j], 0, 0, 0);
    __builtin_amdgcn_s_setprio(0);
    BARRIER();

    // ---- phase 3: read A im4-7 k1; stage T+2 {Bq0,Bq1} (B reads done ph2).
#pragma unroll
    for (int im = 0; im < 4; ++im)
      raB[im][1] = *(const bf16x8*)(Ac + aoff + (im + 4) * 1024 + c1);
    if (s2) {
      async_ld16(Bb + k2, Bc + tl8);
      async_ld16(Bb + (size_t)64 * ld + k2, Bc + 64 * 64 + tl8);
    }
    BARRIER();
    LGKM0();
    __builtin_amdgcn_s_setprio(1);
#pragma unroll
    for (int im = 0; im < 4; ++im)
#pragma unroll
      for (int j = 0; j < 4; ++j)
        acc[im][j] = __builtin_amdgcn_mfma_f32_16x16x32_bf16(
            raA[im][1], rb[j][1], acc[im][j], 0, 0, 0);
    __builtin_amdgcn_s_setprio(0);
    BARRIER();

    // ---- phase 4: stage T+2 {Bq2,Bq3}; counted vmcnt (6 = 3 pairs in flight).
    if (s2) {
      async_ld16(Bb + (size_t)128 * ld + k2, Bc + 128 * 64 + tl8);
      async_ld16(Bb + (size_t)192 * ld + k2, Bc + 192 * 64 + tl8);
    }
    BARRIER();
    LGKM0();
    __builtin_amdgcn_s_setprio(1);
#pragma unroll
    for (int im = 0; im < 4; ++im)
#pragma unroll
      for (int j = 0; j < 4; ++j)
        acc[4 + im][j] = __builtin_amdgcn_mfma_f32_16x16x32_bf16(
            raB[im][1], rb[j][1], acc[4 + im][j], 0, 0, 0);
    __builtin_amdgcn_s_setprio(0);
    if (s2) {
      asm volatile("s_waitcnt vmcnt(6)" ::: "memory");
    } else {
      asm volatile("s_waitcnt vmcnt(0)" ::: "memory");  // epilogue drain
    }
    BARRIER();
  }

  // C/D layout: col = lane&15, row = quad*4 + reg (m89/m91-verified).
  const int mW = m0 + wm * 128 + q * 4;  // + im*16 + r

  if constexpr (MODE == 0) {
    const int sel = n0 >> 10;  // 0=Q 1=K 2=V  (256-tiles never straddle)
    const int nl0 = (n0 & 1023) + wn * 64 + l16;
    if (sel < 2) {
      const float* bias = (sel == 0) ? b0 : b1;
      const float sc = (sel == 0) ? 0.03125f : 1.0f;  // 1/sqrt(1024) in Q
      bf16_t* dst = (sel == 0) ? o0 : o1;
#pragma unroll
      for (int j = 0; j < 4; ++j) {
        const int nl = nl0 + j * 16;
        const float bb = bias[nl];
#pragma unroll
        for (int im = 0; im < 8; ++im) {
          const int mr = mW + im * 16;
#pragma unroll
          for (int r = 0; r < 4; ++r)
            dst[(size_t)(mr + r) * 1024 + nl] =
                (bf16_t)((acc[im][j][r] + bb) * sc);
        }
      }
    } else {
      // V^T via LDS transpose (R11-proven, scaled): two passes of 128 d-rows x
      // 256 m; stride 264 elems keeps the free 2-lanes/bank write pattern and
      // a 16B-aligned, 512B-contiguous drain (full-line stores).
      bf16_t* vs = smem;  // 128*264*2 = 67584 B (K-loop buffers dead)
      const int dg0 = n0 & 1023;
#pragma unroll
      for (int h = 0; h < 2; ++h) {
        if ((wn >> 1) == h) {
#pragma unroll
          for (int j = 0; j < 4; ++j) {
            const int dl = (wn & 1) * 64 + j * 16 + l16;  // 0..127
            const float bb = b2[dg0 + h * 128 + dl];
#pragma unroll
            for (int im = 0; im < 8; ++im) {
              bf16x4 v;
#pragma unroll
              for (int r = 0; r < 4; ++r) v[r] = (bf16_t)(acc[im][j][r] + bb);
              *(bf16x4*)(vs + dl * 264 + wm * 128 + im * 16 + q * 4) = v;
            }
          }
        }
        __syncthreads();
#pragma unroll
        for (int rr = 0; rr < 8; ++rr) {
          const int task = rr * 512 + t;
          const int row = task >> 5, ck = task & 31;
          *(bf16x8*)(o2 + (size_t)(dg0 + h * 128 + row) * 4096 + m0 + ck * 8) =
              *(const bf16x8*)(vs + row * 264 + ck * 8);
        }
        __syncthreads();
      }
    }
  } else if constexpr (MODE == 1) {
    float ps[8][4];
#pragma unroll
    for (int im = 0; im < 8; ++im)
#pragma unroll
      for (int r = 0; r < 4; ++r) ps[im][r] = 0.f;
#pragma unroll
    for (int j = 0; j < 4; ++j) {
      const int n = n0 + wn * 64 + j * 16 + l16;
#pragma unroll
      for (int im = 0; im < 8; ++im) {
        const int mr = mW + im * 16;
#pragma unroll
        for (int r = 0; r < 4; ++r) {
          const float e = __expf(acc[im][j][r]);
          ps[im][r] += e;
          o0[(size_t)(mr + r) * 4096 + n] = (bf16_t)e;
        }
      }
    }
#pragma unroll
    for (int im = 0; im < 8; ++im)
#pragma unroll
      for (int r = 0; r < 4; ++r) {
        float v = ps[im][r];
        v += __shfl_xor(v, 1);
        v += __shfl_xor(v, 2);
        v += __shfl_xor(v, 4);
        v += __shfl_xor(v, 8);
        ps[im][r] = v;
      }
    if (l16 == 0) {
#pragma unroll
      for (int im = 0; im < 8; ++im)
#pragma unroll
        for (int r = 0; r < 4; ++r)
          atomicAdd(rowsum + mW + im * 16 + r, ps[im][r]);
    }
  } else {
    float inv[8][4];
#pragma unroll
    for (int im = 0; im < 8; ++im)
#pragma unroll
      for (int r = 0; r < 4; ++r)
        inv[im][r] = 1.0f / rowsum[mW + im * 16 + r];
    if (zz < 3) {  // bf16 partial (normalized); partials over splits sum to O
      bf16_t* pp = (zz == 0) ? o0 : ((zz == 1) ? o1 : o2);
#pragma unroll
      for (int im = 0; im < 8; ++im) {
        const int mr = mW + im * 16;
#pragma unroll
        for (int j = 0; j < 4; ++j) {
          const int n = n0 + wn * 64 + j * 16 + l16;
#pragma unroll
          for (int r = 0; r < 4; ++r)
            pp[(size_t)(mr + r) * 1024 + n] =
                (bf16_t)(acc[im][j][r] * inv[im][r]);
        }
      }
    } else {  // zz==3: fp32 partial straight into d_out; reduce adds the rest
#pragma unroll
      for (int im = 0; im < 8; ++im) {
        const int mr = mW + im * 16;
#pragma unroll
        for (int j = 0; j < 4; ++j) {
          const int n = n0 + wn * 64 + j * 16 + l16;
#pragma unroll
          for (int r = 0; r < 4; ++r)
            fout[(size_t)(mr + r) * 1024 + n] = acc[im][j][r] * inv[im][r];
        }
      }
    }
  }
}

// Converts X|Wq|Wk|Wv to bf16; last 16 blocks zero rowsum (4096 f32).
__global__ __launch_bounds__(256) void cvt_all(
    const float* __restrict__ X, const float* __restrict__ Wq,
    const float* __restrict__ Wk, const float* __restrict__ Wv,
    bf16_t* __restrict__ Xb, bf16_t* __restrict__ Wb,
    float* __restrict__ rowsum) {
  int i = blockIdx.x * 256 + threadIdx.x;
  if (i >= 1835008) {
    rowsum[i - 1835008] = 0.f;
    return;
  }
  const float* src;
  bf16_t* dst;
  int off;
  if (i < 1048576) {
    src = X; dst = Xb; off = i;
  } else {
    const int w = i - 1048576;
    const int sel = w >> 18;
    off = w & 0x3FFFF;
    src = (sel == 0) ? Wq : ((sel == 1) ? Wk : Wv);
    dst = Wb + (size_t)sel * (1024 * 1024);
  }
  const float4 v = ((const float4*)src)[off];
  bf16x4 o;
  o[0] = (bf16_t)v.x; o[1] = (bf16_t)v.y; o[2] = (bf16_t)v.z; o[3] = (bf16_t)v.w;
  ((bf16x4*)dst)[off] = o;
}

// out[i] += f32(p0[i]) + f32(p1[i]) + f32(p2[i]);  8 elems/thread.
__global__ __launch_bounds__(256) void reduce_out(
    const bf16_t* __restrict__ p0, const bf16_t* __restrict__ p1,
    const bf16_t* __restrict__ p2, float* __restrict__ out) {
  const int i = blockIdx.x * 256 + threadIdx.x;
  const bf16x8 a = ((const bf16x8*)p0)[i];
  const bf16x8 b = ((const bf16x8*)p1)[i];
  const bf16x8 c = ((const bf16x8*)p2)[i];
  float4 lo = ((const float4*)out)[2 * i];
  float4 hi = ((const float4*)out)[2 * i + 1];
  lo.x += (float)a[0] + (float)b[0] + (float)c[0];
  lo.y += (float)a[1] + (float)b[1] + (float)c[1];
  lo.z += (float)a[2] + (float)b[2] + (float)c[2];
  lo.w += (float)a[3] + (float)b[3] + (float)c[3];
  hi.x += (float)a[4] + (float)b[4] + (float)c[4];
  hi.y += (float)a[5] + (float)b[5] + (float)c[5];
  hi.z += (float)a[6] + (float)b[6] + (float)c[6];
  hi.w += (float)a[7] + (float)b[7] + (float)c[7];
  ((float4*)out)[2 * i] = lo;
  ((float4*)out)[2 * i + 1] = hi;
}

extern "C" void kernel_launch(void* const* d_in, const int* in_sizes, int n_in,
                              void* d_out, int out_size, void* d_ws,
                              size_t ws_size, hipStream_t stream) {
  const int S = 4096, D = 1024;
  const float* X  = (const float*)d_in[0];
  const float* Wq = (const float*)d_in[1];
  const float* bq = (const float*)d_in[2];
  const float* Wk = (const float*)d_in[3];
  const float* bk = (const float*)d_in[4];
  const float* Wv = (const float*)d_in[5];
  const float* bv = (const float*)d_in[6];
  float* out = (float*)d_out;

  // ws layout (70 MB bf16 + 16 KB fp32). G3 split-K=4 partials reuse dead
  // regions: Xb (dead after G1), Qb, Kb (dead after G2); z=3 goes to d_out.
  bf16_t* Xb = (bf16_t*)d_ws;            // [4096][1024]
  bf16_t* Wb = Xb + (size_t)S * D;       // [3072][1024]
  bf16_t* Qb = Wb + (size_t)3 * D * D;   // [4096][1024], pre-scaled by 1/32
  bf16_t* Kb = Qb + (size_t)S * D;       // [4096][1024]
  bf16_t* Vt = Kb + (size_t)S * D;       // [1024][4096]  V transposed
  bf16_t* Sc = Vt + (size_t)D * S;       // [4096][4096]  exp(scores)
  float* rowsum = (float*)(Sc + (size_t)S * S);  // [4096]

  // 128 KiB dynamic LDS opt-in (idempotent; not a stream op -> capture-safe).
  static int attr_set = 0;
  if (!attr_set) {
    attr_set = 1;
    (void)hipFuncSetAttribute(reinterpret_cast<const void*>(gemm8<0>),
                              hipFuncAttributeMaxDynamicSharedMemorySize,
                              131072);
    (void)hipFuncSetAttribute(reinterpret_cast<const void*>(gemm8<1>),
                              hipFuncAttributeMaxDynamicSharedMemorySize,
                              131072);
    (void)hipFuncSetAttribute(reinterpret_cast<const void*>(gemm8<2>),
                              hipFuncAttributeMaxDynamicSharedMemorySize,
                              131072);
  }

  cvt_all<<<7184, 256, 0, stream>>>(X, Wq, Wk, Wv, Xb, Wb, rowsum);

  // G1: QKV = Xb @ Wb^T + bias  (M=4096, N=3072, K=1024), 192 blocks
  gemm8<0><<<192, 512, 131072, stream>>>(
      Xb, Wb, D, D, Qb, Kb, Vt, bq, bk, bv, nullptr, nullptr);
  // G2: Sc = exp(Qb @ Kb^T), rowsum partials  (M=N=4096, K=1024), 256 blocks
  gemm8<1><<<256, 512, 131072, stream>>>(
      Qb, Kb, D, D, Sc, nullptr, nullptr, nullptr, nullptr, nullptr, nullptr,
      rowsum);
  // G3: O-partials = (Sc @ Vt^T)/rowsum, K split 4x1024, 256 blocks
  gemm8<2><<<256, 512, 131072, stream>>>(
      Sc, Vt, S, S / 4, Xb, Qb, Kb, nullptr, nullptr, nullptr, out, rowsum);
  // out += p0 + p1 + p2
  reduce_out<<<S * D / 8 / 256, 256, 0, stream>>>(Xb, Qb, Kb, out);
}

// Round 2
// 215.718 us; speedup vs baseline: 1.0113x; 1.0113x over previous
//
#include <hip/hip_runtime.h>
#include <hip/hip_bf16.h>
#include <stdint.h>

// ScaledDotProductAttention S=4096 D=1024 fp32.
// R13 = R12's 256^2/8-wave/4-phase counted-vmcnt schedule with two measured fixes:
//  (1) ALL sched_barrier(0) removed (m141-class pinning: R12 MfmaUtil 22% < R11's
//      26%). Template-exact now: raw s_barrier + asm lgkmcnt(0)/vmcnt(N) with
//      "memory" clobbers only. Code-motion safety w/o sched_barriers:
//      global_load_lds is side-effecting -> cannot cross s_barrier; ds_reads can
//      move but every racy motion is blocked by a "memory"-clobbered waitcnt asm
//      (per-phase proof in the loop comments).
//  (2) Epilogue stores reordered j-INNERMOST: R12 wrote 32B half-line runs with 32
//      stores between line halves -> write-combine defeat -> WRITE_SIZE 70MB vs
//      ~32-40 ideal (2x HBM write inflation). j-inner completes each 128B run with
//      4 consecutive stores.
// Phase map (k-major), reads 8/8/4/4, stages 2/0/4/2, vmcnt(6) steady / 0 at tail:
//   ph1: read A[0..3]k0 + B k0 ; stage T+1 {Aq1,Aq3}->other ; MFMA acc[0..3] k0
//   ph2: read A[0..3]k1 + B k1 ;                              MFMA acc[0..3] k1
//   ph3: read A[4..7]k0        ; stage T+2 {Aq0,Aq2,Bq0,Bq1} ; MFMA acc[4..7] k0
//   ph4: read A[4..7]k1        ; stage T+2 {Bq2,Bq3}; vmcnt(6); MFMA acc[4..7] k1
// Retire proof: Aq0/Aq2 readers (ra0 ph1, ra1 ph2) drain at ph1/ph2 lgkm0 -> ph3
// stage safe. All B readers (rb0 ph1, rb1 ph2) drain by ph2 -> ph3/ph4 B stages
// safe. Aq1/Aq3 readers (rc0 ph3, rc1 ph4) drain at ph4 -> next tile's ph1 stage
// safe. FIFO vmcnt(6) at ph4 drains through this tile's ph1 pair = last pieces of
// tile T+1 -> T+1 fully resident. Tail (s2 false): vmcnt(0).

typedef __bf16 bf16_t;
typedef __bf16 bf16x4 __attribute__((ext_vector_type(4)));
typedef __bf16 bf16x8 __attribute__((ext_vector_type(8)));
typedef float f32x4 __attribute__((ext_vector_type(4)));

#define AS1 __attribute__((address_space(1)))
#define AS3 __attribute__((address_space(3)))

__device__ __forceinline__ void async_ld16(const void* g, void* l) {
  // global -> LDS DMA, 16B/lane; LDS dest is wave-uniform base + lane*16 by HW rule.
  __builtin_amdgcn_global_load_lds((AS1 void*)g, (AS3 void*)l, 16, 0, 0);
}

#define BAR() __builtin_amdgcn_s_barrier()
#define LGKM0() asm volatile("s_waitcnt lgkmcnt(0)" ::: "memory")

// 256x256 tile, BK=64, 8 waves (2M x 4N), per-wave 128x64 output = acc[8][4].
// LDS: 2 bufs x (As 256x64 | Bs 256x64) bf16 = 128 KiB (dynamic).
// MODE 0: QKV epilogue (bias; Q scaled 1/32; V transposed via LDS).
// MODE 1: S epilogue: store exp(acc) bf16 ldc=4096, atomicAdd fp32 row sums.
// MODE 2: O epilogue: zz<3 -> bf16 partial; zz==3 -> fp32 to fout (1/rowsum).
template <int MODE>
__global__ __launch_bounds__(512, 2) void gemm8(
    const bf16_t* __restrict__ A, const bf16_t* __restrict__ B, const int ld,
    const int Klen, bf16_t* __restrict__ o0, bf16_t* __restrict__ o1,
    bf16_t* __restrict__ o2, const float* __restrict__ b0,
    const float* __restrict__ b1, const float* __restrict__ b2,
    float* __restrict__ fout, float* __restrict__ rowsum) {
  extern __shared__ bf16_t smem[];  // 131072 B

  const int t = threadIdx.x;
  const int lane = t & 63;
  const int wave = t >> 6;
  const int wm = wave >> 2;   // 0..1  (M half)
  const int wn = wave & 3;    // 0..3  (N quarter)
  const int q = lane >> 4;
  const int l16 = lane & 15;
  const int xf = l16 & 7;

  // Grid decode: XCD-aware (bid&7 = XCD), bijective per mode.
  int m0, n0, k0 = 0, zz = 0;
  const int bid = blockIdx.x;
  if constexpr (MODE == 0) {
    // 192 blocks = 16m x 12n; per XCD: 4m x 6n region.
    const int x = bid & 7, sl = bid >> 3;  // sl 0..23
    m0 = ((x >> 1) * 4 + (sl & 3)) * 256;
    n0 = ((x & 1) * 6 + (sl >> 2)) * 256;
  } else if constexpr (MODE == 1) {
    // 256 blocks = 16m x 16n; per XCD: 8m x 4n region.
    const int x = bid & 7, sl = bid >> 3;  // sl 0..31
    m0 = ((x >> 2) * 8 + (sl >> 2)) * 256;
    n0 = ((x & 3) * 4 + (sl & 3)) * 256;
  } else {
    // 256 blocks: split-K z = xcd>>1; per XCD: 8m x 4n of one split.
    const int x = bid & 7, sl = bid >> 3;
    zz = x >> 1;
    m0 = ((x & 1) * 8 + (sl >> 2)) * 256;
    n0 = (sl & 3) * 256;
    k0 = zz * Klen;
  }

  // Staging swizzle (R5-proven, conflict-free): GLOBAL chunk = slot ^ (srow&7);
  // LDS stays linear (HW rule). One quarter (64 rows x 64 k) = 1 load/thread.
  const int srow = t >> 3;                      // 0..63
  const int c8s = ((t & 7) ^ (srow & 7)) * 8;
  const bf16_t* Ab = A + (size_t)(m0 + srow) * ld + k0 + c8s;
  const bf16_t* Bb = B + (size_t)(n0 + srow) * ld + k0 + c8s;
  const int tl8 = t * 8;

  // Read-side: frag (im,s) at row wm*128+im*16+l16, LDS slot ((s*4+q)^xf).
  const int aoff = (wm * 128 + l16) * 64;
  const int boff = (wn * 64 + l16) * 64;
  const int c0 = (q ^ xf) * 8;
  const int c1 = ((4 + q) ^ xf) * 8;

  f32x4 acc[8][4];
  const f32x4 zero4 = {0.f, 0.f, 0.f, 0.f};
#pragma unroll
  for (int i = 0; i < 8; ++i)
#pragma unroll
    for (int j = 0; j < 4; ++j) acc[i][j] = zero4;

  const int NT = Klen >> 6;
  bf16_t* buf0 = smem;          // As(16384) | Bs(16384)
  bf16_t* buf1 = smem + 32768;

  // Prologue: tile0 full (8 quarters) -> buf0 (the 8 OLDEST in the vm FIFO),
  // then tile1 {Aq0,Aq2,Bq0..Bq3} -> buf1; vmcnt(6) drains exactly buf0.
  async_ld16(Ab, buf0 + tl8);
  async_ld16(Ab + (size_t)64 * ld, buf0 + 4096 + tl8);
  async_ld16(Ab + (size_t)128 * ld, buf0 + 8192 + tl8);
  async_ld16(Ab + (size_t)192 * ld, buf0 + 12288 + tl8);
  async_ld16(Bb, buf0 + 16384 + tl8);
  async_ld16(Bb + (size_t)64 * ld, buf0 + 16384 + 4096 + tl8);
  async_ld16(Bb + (size_t)128 * ld, buf0 + 16384 + 8192 + tl8);
  async_ld16(Bb + (size_t)192 * ld, buf0 + 16384 + 12288 + tl8);
  async_ld16(Ab + 64, buf1 + tl8);
  async_ld16(Ab + (size_t)128 * ld + 64, buf1 + 8192 + tl8);
  async_ld16(Bb + 64, buf1 + 16384 + tl8);
  async_ld16(Bb + (size_t)64 * ld + 64, buf1 + 16384 + 4096 + tl8);
  async_ld16(Bb + (size_t)128 * ld + 64, buf1 + 16384 + 8192 + tl8);
  async_ld16(Bb + (size_t)192 * ld + 64, buf1 + 16384 + 12288 + tl8);
  asm volatile("s_waitcnt vmcnt(6)" ::: "memory");  // tile0 fully landed
  BAR();

  for (int T = 0; T < NT; ++T) {
    bf16_t* Ac = (T & 1) ? buf1 : buf0;
    bf16_t* An = (T & 1) ? buf0 : buf1;
    bf16_t* Bc = Ac + 16384;
    const int k1 = (T + 1) << 6;
    const int k2 = (T + 2) << 6;
    const bool s1 = (T + 1) < NT;
    const bool s2 = (T + 2) < NT;

    bf16x8 ra0[4], ra1[4], rc0[4], rc1[4], rb0[4], rb1[4];

    // ---- ph1: read A[0..3]k0 + B k0; stage T+1 {Aq1,Aq3} -> An.
    // (ph1 reads can't hoist above prev tile's vmcnt clobber -> buffer resident.)
#pragma unroll
    for (int im = 0; im < 4; ++im)
      ra0[im] = *(const bf16x8*)(Ac + aoff + im * 1024 + c0);
#pragma unroll
    for (int j = 0; j < 4; ++j)
      rb0[j] = *(const bf16x8*)(Bc + boff + j * 1024 + c0);
    if (s1) {
      async_ld16(Ab + (size_t)64 * ld + k1, An + 4096 + tl8);
      async_ld16(Ab + (size_t)192 * ld + k1, An + 12288 + tl8);
    }
    BAR();
    LGKM0();
    __builtin_amdgcn_s_setprio(1);
#pragma unroll
    for (int im = 0; im < 4; ++im)
#pragma unroll
      for (int j = 0; j < 4; ++j)
        acc[im][j] = __builtin_amdgcn_mfma_f32_16x16x32_bf16(
            ra0[im], rb0[j], acc[im][j], 0, 0, 0);
    __builtin_amdgcn_s_setprio(0);
    BAR();

    // ---- ph2: read A[0..3]k1 + B k1 (no stage; nothing can race here).
#pragma unroll
    for (int im = 0; im < 4; ++im)
      ra1[im] = *(const bf16x8*)(Ac + aoff + im * 1024 + c1);
#pragma unroll
    for (int j = 0; j < 4; ++j)
      rb1[j] = *(const bf16x8*)(Bc + boff + j * 1024 + c1);
    BAR();
    LGKM0();
    __builtin_amdgcn_s_setprio(1);
#pragma unroll
    for (int im = 0; im < 4; ++im)
#pragma unroll
      for (int j = 0; j < 4; ++j)
        acc[im][j] = __builtin_amdgcn_mfma_f32_16x16x32_bf16(
            ra1[im], rb1[j], acc[im][j], 0, 0, 0);
    __builtin_amdgcn_s_setprio(0);
    BAR();

    // ---- ph3: read A[4..7]k0; stage T+2 {Aq0,Aq2,Bq0,Bq1} -> Ac/Bc.
    // Safe: Aq0/Aq2 readers drained ph1/ph2; all B readers drained ph2.
#pragma unroll
    for (int im = 0; im < 4; ++im)
      rc0[im] = *(const bf16x8*)(Ac + aoff + (im + 4) * 1024 + c0);
    if (s2) {
      async_ld16(Ab + k2, Ac + tl8);
      async_ld16(Ab + (size_t)128 * ld + k2, Ac + 8192 + tl8);
      async_ld16(Bb + k2, Bc + tl8);
      async_ld16(Bb + (size_t)64 * ld + k2, Bc + 4096 + tl8);
    }
    BAR();
    LGKM0();
    __builtin_amdgcn_s_setprio(1);
#pragma unroll
    for (int im = 0; im < 4; ++im)
#pragma unroll
      for (int j = 0; j < 4; ++j)
        acc[4 + im][j] = __builtin_amdgcn_mfma_f32_16x16x32_bf16(
            rc0[im], rb0[j], acc[4 + im][j], 0, 0, 0);
    __builtin_amdgcn_s_setprio(0);
    BAR();

    // ---- ph4: read A[4..7]k1; stage T+2 {Bq2,Bq3}; counted vmcnt.
#pragma unroll
    for (int im = 0; im < 4; ++im)
      rc1[im] = *(const bf16x8*)(Ac + aoff + (im + 4) * 1024 + c1);
    if (s2) {
      async_ld16(Bb + (size_t)128 * ld + k2, Bc + 8192 + tl8);
      async_ld16(Bb + (size_t)192 * ld + k2, Bc + 12288 + tl8);
    }
    BAR();
    LGKM0();
    __builtin_amdgcn_s_setprio(1);
#pragma unroll
    for (int im = 0; im < 4; ++im)
#pragma unroll
      for (int j = 0; j < 4; ++j)
        acc[4 + im][j] = __builtin_amdgcn_mfma_f32_16x16x32_bf16(
            rc1[im], rb1[j], acc[4 + im][j], 0, 0, 0);
    __builtin_amdgcn_s_setprio(0);
    if (s2) {
      asm volatile("s_waitcnt vmcnt(6)" ::: "memory");  // 3 pairs in flight
    } else {
      asm volatile("s_waitcnt vmcnt(0)" ::: "memory");  // tail drain (T>=NT-2)
    }
    BAR();
  }

  // C/D layout: col = lane&15, row = quad*4 + reg (m89/m91-verified).
  const int mW = m0 + wm * 128 + q * 4;  // + im*16 + r

  if constexpr (MODE == 0) {
    const int sel = n0 >> 10;  // 0=Q 1=K 2=V  (256-tiles never straddle)
    const int nl0 = (n0 & 1023) + wn * 64 + l16;
    if (sel < 2) {
      const float* bias = (sel == 0) ? b0 : b1;
      const float sc = (sel == 0) ? 0.03125f : 1.0f;  // 1/sqrt(1024) in Q
      bf16_t* dst = (sel == 0) ? o0 : o1;
      float bb[4];
#pragma unroll
      for (int j = 0; j < 4; ++j) bb[j] = bias[nl0 + j * 16];
      // j INNERMOST: 4 consecutive stores complete each 128B run (R13 fix).
#pragma unroll
      for (int im = 0; im < 8; ++im) {
        const int mr = mW + im * 16;
#pragma unroll
        for (int r = 0; r < 4; ++r)
#pragma unroll
          for (int j = 0; j < 4; ++j)
            dst[(size_t)(mr + r) * 1024 + nl0 + j * 16] =
                (bf16_t)((acc[im][j][r] + bb[j]) * sc);
      }
    } else {
      // V^T via LDS transpose (R11-proven, scaled): two passes of 128 d-rows x
      // 256 m; stride 264 elems keeps the free 2-lanes/bank write pattern and
      // a 16B-aligned, 512B-contiguous drain (full-line stores).
      bf16_t* vs = smem;  // 128*264*2 = 67584 B (K-loop buffers dead)
      const int dg0 = n0 & 1023;
#pragma unroll
      for (int h = 0; h < 2; ++h) {
        if ((wn >> 1) == h) {
#pragma unroll
          for (int j = 0; j < 4; ++j) {
            const int dl = (wn & 1) * 64 + j * 16 + l16;  // 0..127
            const float bb = b2[dg0 + h * 128 + dl];
#pragma unroll
            for (int im = 0; im < 8; ++im) {
              bf16x4 v;
#pragma unroll
              for (int r = 0; r < 4; ++r) v[r] = (bf16_t)(acc[im][j][r] + bb);
              *(bf16x4*)(vs + dl * 264 + wm * 128 + im * 16 + q * 4) = v;
            }
          }
        }
        __syncthreads();
#pragma unroll
        for (int rr = 0; rr < 8; ++rr) {
          const int task = rr * 512 + t;
          const int row = task >> 5, ck = task & 31;
          *(bf16x8*)(o2 + (size_t)(dg0 + h * 128 + row) * 4096 + m0 + ck * 8) =
              *(const bf16x8*)(vs + row * 264 + ck * 8);
        }
        __syncthreads();
      }
    }
  } else if constexpr (MODE == 1) {
    float ps[8][4];
#pragma unroll
    for (int im = 0; im < 8; ++im)
#pragma unroll
      for (int r = 0; r < 4; ++r) ps[im][r] = 0.f;
    const int nb = n0 + wn * 64 + l16;
    // j INNERMOST: complete 128B runs back-to-back (R13 write-combine fix).
#pragma unroll
    for (int im = 0; im < 8; ++im) {
      const int mr = mW + im * 16;
#pragma unroll
      for (int r = 0; r < 4; ++r)
#pragma unroll
        for (int j = 0; j < 4; ++j) {
          const float e = __expf(acc[im][j][r]);
          ps[im][r] += e;
          o0[(size_t)(mr + r) * 4096 + nb + j * 16] = (bf16_t)e;
        }
    }
#pragma unroll
    for (int im = 0; im < 8; ++im)
#pragma unroll
      for (int r = 0; r < 4; ++r) {
        float v = ps[im][r];
        v += __shfl_xor(v, 1);
        v += __shfl_xor(v, 2);
        v += __shfl_xor(v, 4);
        v += __shfl_xor(v, 8);
        ps[im][r] = v;
      }
    if (l16 == 0) {
#pragma unroll
      for (int im = 0; im < 8; ++im)
#pragma unroll
        for (int r = 0; r < 4; ++r)
          atomicAdd(rowsum + mW + im * 16 + r, ps[im][r]);
    }
  } else {
    float inv[8][4];
#pragma unroll
    for (int im = 0; im < 8; ++im)
#pragma unroll
      for (int r = 0; r < 4; ++r)
        inv[im][r] = 1.0f / rowsum[mW + im * 16 + r];
    const int nb = n0 + wn * 64 + l16;
    if (zz < 3) {  // bf16 partial (normalized); partials over splits sum to O
      bf16_t* pp = (zz == 0) ? o0 : ((zz == 1) ? o1 : o2);
#pragma unroll
      for (int im = 0; im < 8; ++im) {
        const int mr = mW + im * 16;
#pragma unroll
        for (int r = 0; r < 4; ++r) {
          const float iv = inv[im][r];
#pragma unroll
          for (int j = 0; j < 4; ++j)
            pp[(size_t)(mr + r) * 1024 + nb + j * 16] =
                (bf16_t)(acc[im][j][r] * iv);
        }
      }
    } else {  // zz==3: fp32 partial straight into d_out; reduce adds the rest
#pragma unroll
      for (int im = 0; im < 8; ++im) {
        const int mr = mW + im * 16;
#pragma unroll
        for (int r = 0; r < 4; ++r) {
          const float iv = inv[im][r];
#pragma unroll
          for (int j = 0; j < 4; ++j)
            fout[(size_t)(mr + r) * 1024 + nb + j * 16] = acc[im][j][r] * iv;
        }
      }
    }
  }
}

// Converts X|Wq|Wk|Wv to bf16; last 16 blocks zero rowsum (4096 f32).
__global__ __launch_bounds__(256) void cvt_all(
    const float* __restrict__ X, const float* __restrict__ Wq,
    const float* __restrict__ Wk, const float* __restrict__ Wv,
    bf16_t* __restrict__ Xb, bf16_t* __restrict__ Wb,
    float* __restrict__ rowsum) {
  int i = blockIdx.x * 256 + threadIdx.x;
  if (i >= 1835008) {
    rowsum[i - 1835008] = 0.f;
    return;
  }
  const float* src;
  bf16_t* dst;
  int off;
  if (i < 1048576) {
    src = X; dst = Xb; off = i;
  } else {
    const int w = i - 1048576;
    const int sel = w >> 18;
    off = w & 0x3FFFF;
    src = (sel == 0) ? Wq : ((sel == 1) ? Wk : Wv);
    dst = Wb + (size_t)sel * (1024 * 1024);
  }
  const float4 v = ((const float4*)src)[off];
  bf16x4 o;
  o[0] = (bf16_t)v.x; o[1] = (bf16_t)v.y; o[2] = (bf16_t)v.z; o[3] = (bf16_t)v.w;
  ((bf16x4*)dst)[off] = o;
}

// out[i] += f32(p0[i]) + f32(p1[i]) + f32(p2[i]);  8 elems/thread.
__global__ __launch_bounds__(256) void reduce_out(
    const bf16_t* __restrict__ p0, const bf16_t* __restrict__ p1,
    const bf16_t* __restrict__ p2, float* __restrict__ out) {
  const int i = blockIdx.x * 256 + threadIdx.x;
  const bf16x8 a = ((const bf16x8*)p0)[i];
  const bf16x8 b = ((const bf16x8*)p1)[i];
  const bf16x8 c = ((const bf16x8*)p2)[i];
  float4 lo = ((const float4*)out)[2 * i];
  float4 hi = ((const float4*)out)[2 * i + 1];
  lo.x += (float)a[0] + (float)b[0] + (float)c[0];
  lo.y += (float)a[1] + (float)b[1] + (float)c[1];
  lo.z += (float)a[2] + (float)b[2] + (float)c[2];
  lo.w += (float)a[3] + (float)b[3] + (float)c[3];
  hi.x += (float)a[4] + (float)b[4] + (float)c[4];
  hi.y += (float)a[5] + (float)b[5] + (float)c[5];
  hi.z += (float)a[6] + (float)b[6] + (float)c[6];
  hi.w += (float)a[7] + (float)b[7] + (float)c[7];
  ((float4*)out)[2 * i] = lo;
  ((float4*)out)[2 * i + 1] = hi;
}

extern "C" void kernel_launch(void* const* d_in, const int* in_sizes, int n_in,
                              void* d_out, int out_size, void* d_ws,
                              size_t ws_size, hipStream_t stream) {
  const int S = 4096, D = 1024;
  const float* X  = (const float*)d_in[0];
  const float* Wq = (const float*)d_in[1];
  const float* bq = (const float*)d_in[2];
  const float* Wk = (const float*)d_in[3];
  const float* bk = (const float*)d_in[4];
  const float* Wv = (const float*)d_in[5];
  const float* bv = (const float*)d_in[6];
  float* out = (float*)d_out;

  // ws layout (70 MB bf16 + 16 KB fp32). G3 split-K=4 partials reuse dead
  // regions: Xb (dead after G1), Qb, Kb (dead after G2); z=3 goes to d_out.
  bf16_t* Xb = (bf16_t*)d_ws;            // [4096][1024]
  bf16_t* Wb = Xb + (size_t)S * D;       // [3072][1024]
  bf16_t* Qb = Wb + (size_t)3 * D * D;   // [4096][1024], pre-scaled by 1/32
  bf16_t* Kb = Qb + (size_t)S * D;       // [4096][1024]
  bf16_t* Vt = Kb + (size_t)S * D;       // [1024][4096]  V transposed
  bf16_t* Sc = Vt + (size_t)D * S;       // [4096][4096]  exp(scores)
  float* rowsum = (float*)(Sc + (size_t)S * S);  // [4096]

  // 128 KiB dynamic LDS opt-in (idempotent; not a stream op -> capture-safe).
  static int attr_set = 0;
  if (!attr_set) {
    attr_set = 1;
    (void)hipFuncSetAttribute(reinterpret_cast<const void*>(gemm8<0>),
                              hipFuncAttributeMaxDynamicSharedMemorySize,
                              131072);
    (void)hipFuncSetAttribute(reinterpret_cast<const void*>(gemm8<1>),
                              hipFuncAttributeMaxDynamicSharedMemorySize,
                              131072);
    (void)hipFuncSetAttribute(reinterpret_cast<const void*>(gemm8<2>),
                              hipFuncAttributeMaxDynamicSharedMemorySize,
                              131072);
  }

  cvt_all<<<7184, 256, 0, stream>>>(X, Wq, Wk, Wv, Xb, Wb, rowsum);

  // G1: QKV = Xb @ Wb^T + bias  (M=4096, N=3072, K=1024), 192 blocks
  gemm8<0><<<192, 512, 131072, stream>>>(
      Xb, Wb, D, D, Qb, Kb, Vt, bq, bk, bv, nullptr, nullptr);
  // G2: Sc = exp(Qb @ Kb^T), rowsum partials  (M=N=4096, K=1024), 256 blocks
  gemm8<1><<<256, 512, 131072, stream>>>(
      Qb, Kb, D, D, Sc, nullptr, nullptr, nullptr, nullptr, nullptr, nullptr,
      rowsum);
  // G3: O-partials = (Sc @ Vt^T)/rowsum, K split 4x1024, 256 blocks
  gemm8<2><<<256, 512, 131072, stream>>>(
      Sc, Vt, S, S / 4, Xb, Qb, Kb, nullptr, nullptr, nullptr, out, rowsum);
  // out += p0 + p1 + p2
  reduce_out<<<S * D / 8 / 256, 256, 0, stream>>>(Xb, Qb, Kb, out);
}

// Round 4
// 211.532 us; speedup vs baseline: 1.0313x; 1.0198x over previous
//
#include <hip/hip_runtime.h>
#include <hip/hip_bf16.h>
#include <stdint.h>

// ScaledDotProductAttention S=4096 D=1024 fp32.
// R14 = R11 (proven 203.9-208.9us) + two measured fixes; the 256^2/8-wave/4-phase
// rewrite (R12/R13) is abandoned: it measured 563-590 TF vs R11's 670 (m196-class
// coarse-split regression) AND its 128KB-LDS/1-block-CU config showed 0.7 blocks/CU
// average residency (dispatch queueing, ~2x makespan).
//  Fix 1: __launch_bounds__(256,4). R11's Occupancy 26% = 2 blocks/CU => unified
//   regs in (170,256] though true need is 64 VGPR + 64 AGPR = 128: the (256,2)
//   budget let the compiler pad. Cap at 128 (=2048/16) -> 4 blocks/CU residency
//   (m114: wave-level overlap is what lifts the m97 structure toward ~900 TF).
//  Fix 2 (R13-measured, WRITE 70->36.9 MB there): j-INNERMOST direct stores.
//   R11 wrote 32B half-line runs with 32 stores between line halves (j outer) ->
//   write-combine defeat (G2 WRITE 41.5 vs 36.9 ideal). j-inner completes each
//   128B run with 4 consecutive stores.
// Structure (unchanged from R11): cvt | G1 QKV (V^T via LDS) | G2 exp(QK^T)+rowsum
// | G3 split-K=4 XCD | reduce. BN=128 BK=64 tile, 4 waves, 16x16x32 MFMA,
// global_load_lds w=16, single-buffered (multi-block/CU provides the overlap).
// (R14 resubmission: previous bench attempt died on container acquire, not code.)

typedef __bf16 bf16_t;
typedef __bf16 bf16x4 __attribute__((ext_vector_type(4)));
typedef __bf16 bf16x8 __attribute__((ext_vector_type(8)));
typedef float f32x4 __attribute__((ext_vector_type(4)));

#define AS1 __attribute__((address_space(1)))
#define AS3 __attribute__((address_space(3)))

__device__ __forceinline__ void async_ld16(const void* g, void* l) {
  // global -> LDS DMA, 16B/lane; LDS dest is wave-uniform base + lane*16 by HW rule.
  __builtin_amdgcn_global_load_lds((AS1 void*)g, (AS3 void*)l, 16, 0, 0);
}

// BN=128, BK=64 GEMM tile, 4 waves, mfma_f32_16x16x32_bf16, global_load_lds w=16.
// As/Bs must be ONE contiguous 32KB LDS block (As first): the MODE-0 V^T epilogue
// reuses 17.4KB of it as a transpose staging tile after the K-loop.
// MODE 0: QKV epilogue (bias; Q scaled 1/32; V transposed via LDS).
// MODE 1: S epilogue: store exp(acc) bf16 ldc=4096, atomicAdd fp32 row sums.
// MODE 2: O epilogue: zz<3 -> bf16 partial to o_zz; zz==3 -> fp32 to fout (1/rowsum).
template <int MODE>
__device__ void gemm_core(bf16_t* As, bf16_t* Bs, const int t, const int m0,
                          const int n0, const int k0, const int zz,
                          const bf16_t* __restrict__ A,
                          const bf16_t* __restrict__ B, const int ld,
                          const int Klen, bf16_t* __restrict__ o0,
                          bf16_t* __restrict__ o1, bf16_t* __restrict__ o2,
                          const float* __restrict__ b0,
                          const float* __restrict__ b1,
                          const float* __restrict__ b2,
                          float* __restrict__ fout,
                          float* __restrict__ rowsum) {
  constexpr int BN = 128, BK = 64;
  constexpr int NF = BN / 32;   // n-frags per wave
  constexpr int KS = BK / 32;   // mfma k-steps per tile
  constexpr int CH = BK / 8;    // 16B chunks per LDS row
  constexpr int RS = 256 / CH;  // rows staged per DMA round

  const int lane = t & 63;
  const int wave = t >> 6;
  const int wm = wave >> 1;
  const int wn = wave & 1;
  const int q = lane >> 4;
  const int l16 = lane & 15;
  const int wnoff = wn * (BN / 2);

  const f32x4 zero4 = {0.f, 0.f, 0.f, 0.f};
  f32x4 acc[4][NF];
#pragma unroll
  for (int i = 0; i < 4; ++i)
#pragma unroll
    for (int j = 0; j < NF; ++j) acc[i][j] = zero4;

  // Staging swizzle (R5-proven, conflict-free): GLOBAL chunk = slot ^ (srow&7);
  // read side inverts with xf = l16&7 (per-lane constant on rows 16a+l16).
  const int srow = t / CH;
  const int schunk = (t % CH) ^ (srow & 7);
  const bf16_t* Ab = A + (size_t)(m0 + srow) * ld + k0 + schunk * 8;
  const bf16_t* Bb = B + (size_t)(n0 + srow) * ld + k0 + schunk * 8;
  bf16_t* Asl = As + t * 8;
  bf16_t* Bsl = Bs + t * 8;

  const int xf = l16 & 7;
  const int ar = wm * 64 + l16;
  const int br = wnoff + l16;

  for (int kt = 0; kt < Klen; kt += BK) {
#pragma unroll
    for (int rr = 0; rr < 128 / RS; ++rr)
      async_ld16(Ab + kt + (size_t)(rr * RS) * ld, Asl + rr * RS * BK);
#pragma unroll
    for (int rr = 0; rr < BN / RS; ++rr)
      async_ld16(Bb + kt + (size_t)(rr * RS) * ld, Bsl + rr * RS * BK);
    __syncthreads();

#pragma unroll
    for (int s = 0; s < KS; ++s) {
      bf16x8 fa[4], fb[NF];
#pragma unroll
      for (int im = 0; im < 4; ++im)
        fa[im] = *(const bf16x8*)(As + (ar + im * 16) * BK +
                                  (((s * 4 + q) ^ xf) * 8));
#pragma unroll
      for (int j = 0; j < NF; ++j)
        fb[j] = *(const bf16x8*)(Bs + (br + j * 16) * BK +
                                 (((s * 4 + q) ^ xf) * 8));
#pragma unroll
      for (int im = 0; im < 4; ++im)
#pragma unroll
        for (int j = 0; j < NF; ++j)
          acc[im][j] = __builtin_amdgcn_mfma_f32_16x16x32_bf16(
              fa[im], fb[j], acc[im][j], 0, 0, 0);
    }
    __syncthreads();
  }

  // C/D layout: col = lane&15, row = quad*4 + reg (m89/m91-verified).
  const int mBase = m0 + wm * 64 + q * 4;

  if constexpr (MODE == 0) {
    const int sel = n0 >> 10;  // 0=Q 1=K 2=V
    const int nl0 = (n0 & 1023) + wnoff + l16;
    if (sel < 2) {
      const float* bias = (sel == 0) ? b0 : b1;
      const float sc = (sel == 0) ? 0.03125f : 1.0f;  // 1/sqrt(1024) in Q
      bf16_t* dst = (sel == 0) ? o0 : o1;
      float bb[NF];
#pragma unroll
      for (int j = 0; j < NF; ++j) bb[j] = bias[nl0 + j * 16];
      // j INNERMOST: 4 consecutive stores per row run (R13-measured WC fix).
#pragma unroll
      for (int im = 0; im < 4; ++im) {
        const int mr = mBase + im * 16;
#pragma unroll
        for (int r = 0; r < 4; ++r)
#pragma unroll
          for (int j = 0; j < NF; ++j)
            dst[(size_t)(mr + r) * 1024 + nl0 + j * 16] =
                (bf16_t)((acc[im][j][r] + bb[j]) * sc);
      }
    } else {
      // V^T epilogue via LDS transpose (R11). Direct 8B scatter (8KB lane
      // stride) caused RMW inflation (R8: +16MB WRITE). Two passes, one per
      // wn-half (64 d-rows x 128 keys); LDS row stride 136 elems: 16B-aligned
      // (272B), write banks (4*l16+8*im+2*q) = 2 lanes/bank-pair (free, m136);
      // drain is 16B/lane, 256B contiguous per Vt row -> full-line stores.
      bf16_t* vs = As;  // needs 64*136*2B = 17.4KB of the contiguous As+Bs 32KB
      const int dg0 = (n0 & 1023);
#pragma unroll
      for (int h = 0; h < 2; ++h) {
        if (wn == h) {
#pragma unroll
          for (int j = 0; j < NF; ++j) {
            const int dl = j * 16 + l16;  // 0..63 within this half
            const float bb = b2[dg0 + h * 64 + dl];
#pragma unroll
            for (int im = 0; im < 4; ++im) {
              bf16x4 v;
#pragma unroll
              for (int r = 0; r < 4; ++r) v[r] = (bf16_t)(acc[im][j][r] + bb);
              *(bf16x4*)(vs + dl * 136 + wm * 64 + im * 16 + q * 4) = v;
            }
          }
        }
        __syncthreads();
#pragma unroll
        for (int rr = 0; rr < 4; ++rr) {
          const int task = rr * 256 + t;
          const int row = task >> 4, ck = task & 15;
          *(bf16x8*)(o2 + (size_t)(dg0 + h * 64 + row) * 4096 + m0 + ck * 8) =
              *(const bf16x8*)(vs + row * 136 + ck * 8);
        }
        __syncthreads();
      }
    }
  } else if constexpr (MODE == 1) {
    float ps[4][4];
#pragma unroll
    for (int im = 0; im < 4; ++im)
#pragma unroll
      for (int r = 0; r < 4; ++r) ps[im][r] = 0.f;
    const int nb = n0 + wnoff + l16;
    // j INNERMOST: complete 128B runs back-to-back (R13-measured WC fix).
#pragma unroll
    for (int im = 0; im < 4; ++im) {
      const int mr = mBase + im * 16;
#pragma unroll
      for (int r = 0; r < 4; ++r)
#pragma unroll
        for (int j = 0; j < NF; ++j) {
          const float e = __expf(acc[im][j][r]);
          ps[im][r] += e;
          o0[(size_t)(mr + r) * 4096 + nb + j * 16] = (bf16_t)e;
        }
    }
#pragma unroll
    for (int im = 0; im < 4; ++im)
#pragma unroll
      for (int r = 0; r < 4; ++r) {
        float v = ps[im][r];
        v += __shfl_xor(v, 1);
        v += __shfl_xor(v, 2);
        v += __shfl_xor(v, 4);
        v += __shfl_xor(v, 8);
        ps[im][r] = v;
      }
    if (l16 == 0) {
#pragma unroll
      for (int im = 0; im < 4; ++im)
#pragma unroll
        for (int r = 0; r < 4; ++r)
          atomicAdd(rowsum + mBase + im * 16 + r, ps[im][r]);
    }
  } else {
    float inv[4][4];
#pragma unroll
    for (int im = 0; im < 4; ++im)
#pragma unroll
      for (int r = 0; r < 4; ++r)
        inv[im][r] = 1.0f / rowsum[mBase + im * 16 + r];
    const int nb = n0 + wnoff + l16;
    if (zz < 3) {  // bf16 partial (normalized); partials over splits sum to O
      bf16_t* pp = (zz == 0) ? o0 : ((zz == 1) ? o1 : o2);
#pragma unroll
      for (int im = 0; im < 4; ++im) {
        const int mr = mBase + im * 16;
#pragma unroll
        for (int r = 0; r < 4; ++r) {
          const float iv = inv[im][r];
#pragma unroll
          for (int j = 0; j < NF; ++j)
            pp[(size_t)(mr + r) * 1024 + nb + j * 16] =
                (bf16_t)(acc[im][j][r] * iv);
        }
      }
    } else {  // zz==3: fp32 partial straight into d_out; reduce adds the rest
#pragma unroll
      for (int im = 0; im < 4; ++im) {
        const int mr = mBase + im * 16;
#pragma unroll
        for (int r = 0; r < 4; ++r) {
          const float iv = inv[im][r];
#pragma unroll
          for (int j = 0; j < NF; ++j)
            fout[(size_t)(mr + r) * 1024 + nb + j * 16] = acc[im][j][r] * iv;
        }
      }
    }
  }
}

template <int MODE>
__global__ __launch_bounds__(256, 4) void gemm_sep(
    const bf16_t* __restrict__ A, const bf16_t* __restrict__ B, const int ld,
    const int Klen,
    bf16_t* __restrict__ o0, bf16_t* __restrict__ o1, bf16_t* __restrict__ o2,
    const float* __restrict__ b0, const float* __restrict__ b1,
    const float* __restrict__ b2, float* __restrict__ fout,
    float* __restrict__ rowsum) {
  __shared__ bf16_t smem[2 * 128 * 64];  // contiguous As|Bs (32KB)
  bf16_t* As = smem;
  bf16_t* Bs = smem + 128 * 64;
  int m0, n0, k0 = 0, zz = 0;
  if constexpr (MODE == 1) {
    // XCD-aware swizzle (grid 32x32): xcd owns a 16m x 8n region (bijective).
    const int bid = blockIdx.y * 32 + blockIdx.x;
    const int xcd = bid & 7, sl = bid >> 3;
    m0 = ((xcd >> 2) * 16 + (sl >> 3)) * 128;
    n0 = ((xcd & 3) * 8 + (sl & 7)) * 128;
  } else if constexpr (MODE == 2) {
    // XCD partition (1D grid 1024): each XCD owns (z, m-half) = 128 tiles,
    // L2 footprint A 4MB + B 2MB (R7-verified: FETCH 135 -> 50 MB).
    const int lin = blockIdx.x;
    const int xcd = lin & 7, s = lin >> 3;
    zz = xcd >> 1;
    m0 = ((xcd & 1) * 16 + (s >> 3)) * 128;
    n0 = (s & 7) * 128;
    k0 = zz * Klen;
  } else {
    n0 = blockIdx.x * 128;
    m0 = blockIdx.y * 128;
  }
  gemm_core<MODE>(As, Bs, threadIdx.x, m0, n0, k0, zz, A, B, ld, Klen, o0, o1,
                  o2, b0, b1, b2, fout, rowsum);
}

// Converts X|Wq|Wk|Wv to bf16; last 16 blocks zero rowsum (4096 f32).
__global__ __launch_bounds__(256) void cvt_all(
    const float* __restrict__ X, const float* __restrict__ Wq,
    const float* __restrict__ Wk, const float* __restrict__ Wv,
    bf16_t* __restrict__ Xb, bf16_t* __restrict__ Wb,
    float* __restrict__ rowsum) {
  int i = blockIdx.x * 256 + threadIdx.x;
  if (i >= 1835008) {
    rowsum[i - 1835008] = 0.f;
    return;
  }
  const float* src;
  bf16_t* dst;
  int off;
  if (i < 1048576) {
    src = X; dst = Xb; off = i;
  } else {
    const int w = i - 1048576;
    const int sel = w >> 18;
    off = w & 0x3FFFF;
    src = (sel == 0) ? Wq : ((sel == 1) ? Wk : Wv);
    dst = Wb + (size_t)sel * (1024 * 1024);
  }
  const float4 v = ((const float4*)src)[off];
  bf16x4 o;
  o[0] = (bf16_t)v.x; o[1] = (bf16_t)v.y; o[2] = (bf16_t)v.z; o[3] = (bf16_t)v.w;
  ((bf16x4*)dst)[off] = o;
}

// out[i] += f32(p0[i]) + f32(p1[i]) + f32(p2[i]);  8 elems/thread.
__global__ __launch_bounds__(256) void reduce_out(
    const bf16_t* __restrict__ p0, const bf16_t* __restrict__ p1,
    const bf16_t* __restrict__ p2, float* __restrict__ out) {
  const int i = blockIdx.x * 256 + threadIdx.x;
  const bf16x8 a = ((const bf16x8*)p0)[i];
  const bf16x8 b = ((const bf16x8*)p1)[i];
  const bf16x8 c = ((const bf16x8*)p2)[i];
  float4 lo = ((const float4*)out)[2 * i];
  float4 hi = ((const float4*)out)[2 * i + 1];
  lo.x += (float)a[0] + (float)b[0] + (float)c[0];
  lo.y += (float)a[1] + (float)b[1] + (float)c[1];
  lo.z += (float)a[2] + (float)b[2] + (float)c[2];
  lo.w += (float)a[3] + (float)b[3] + (float)c[3];
  hi.x += (float)a[4] + (float)b[4] + (float)c[4];
  hi.y += (float)a[5] + (float)b[5] + (float)c[5];
  hi.z += (float)a[6] + (float)b[6] + (float)c[6];
  hi.w += (float)a[7] + (float)b[7] + (float)c[7];
  ((float4*)out)[2 * i] = lo;
  ((float4*)out)[2 * i + 1] = hi;
}

extern "C" void kernel_launch(void* const* d_in, const int* in_sizes, int n_in,
                              void* d_out, int out_size, void* d_ws,
                              size_t ws_size, hipStream_t stream) {
  const int S = 4096, D = 1024;
  const float* X  = (const float*)d_in[0];
  const float* Wq = (const float*)d_in[1];
  const float* bq = (const float*)d_in[2];
  const float* Wk = (const float*)d_in[3];
  const float* bk = (const float*)d_in[4];
  const float* Wv = (const float*)d_in[5];
  const float* bv = (const float*)d_in[6];
  float* out = (float*)d_out;

  // ws layout (70 MB bf16 + 16 KB fp32). G3 split-K=4 partials reuse dead
  // regions: Xb (dead after G1), Qb, Kb (dead after G2); z=3 goes to d_out.
  bf16_t* Xb = (bf16_t*)d_ws;            // [4096][1024]
  bf16_t* Wb = Xb + (size_t)S * D;       // [3072][1024]
  bf16_t* Qb = Wb + (size_t)3 * D * D;   // [4096][1024], pre-scaled by 1/32
  bf16_t* Kb = Qb + (size_t)S * D;       // [4096][1024]
  bf16_t* Vt = Kb + (size_t)S * D;       // [1024][4096]  V transposed
  bf16_t* Sc = Vt + (size_t)D * S;       // [4096][4096]  exp(scores)
  float* rowsum = (float*)(Sc + (size_t)S * S);  // [4096]

  cvt_all<<<7184, 256, 0, stream>>>(X, Wq, Wk, Wv, Xb, Wb, rowsum);

  // G1: QKV = Xb @ Wb^T + bias  (M=4096, N=3072, K=1024), grid 768 (3/CU)
  gemm_sep<0><<<dim3(24, 32), 256, 0, stream>>>(
      Xb, Wb, D, D, Qb, Kb, Vt, bq, bk, bv, nullptr, nullptr);
  // G2: Sc = exp(Qb @ Kb^T), rowsum partials  (M=N=4096, K=1024), grid 1024
  gemm_sep<1><<<dim3(32, 32), 256, 0, stream>>>(
      Qb, Kb, D, D, Sc, nullptr, nullptr, nullptr, nullptr, nullptr, nullptr,
      rowsum);
  // G3: O-partials = (Sc @ Vt^T)/rowsum, K split 4x1024, grid 1024, XCD decode
  gemm_sep<2><<<1024, 256, 0, stream>>>(
      Sc, Vt, S, S / 4, Xb, Qb, Kb, nullptr, nullptr, nullptr, out, rowsum);
  // out += p0 + p1 + p2
  reduce_out<<<S * D / 8 / 256, 256, 0, stream>>>(Xb, Qb, Kb, out);
}

// Round 5
// 205.034 us; speedup vs baseline: 1.0640x; 1.0317x over previous
//
#include <hip/hip_runtime.h>
#include <hip/hip_bf16.h>
#include <stdint.h>

// ScaledDotProductAttention S=4096 D=1024 fp32.
// R15: staging-bandwidth model (built R14): every GEMM dispatch time == staged
// L2->LDS bytes / ~10.1 TB/s (G2: 512 MB / 50.7us measured, exact). MfmaUtil is a
// passenger. Only lever: staged bytes = tile intensity. 256^2 tile halves bytes
// vs 128^2 (128 vs 64 FLOP/B). R12/R13's 256^2 failed NOT on tile but on schedule:
// 2-DMA-per-phase bursts starved DMA concurrency (4.4 TB/s). R15 keeps the PROVEN
// m97 2-barrier loop at 256^2/8-wave with dbuf LDS (2x64KB): burst-stage ALL 8
// DMAs of tile T+1, compute tile T, __syncthreads (auto vmcnt(0) drains at end of
// compute => DMAs get the whole MFMA phase to land; burst depth per CU identical
// to the proven 128^2 config => 10 TB/s should hold).
// Epilogues/decodes/swizzle identical to R12/R13 (correctness-verified, passed;
// j-innermost stores R13-measured: WRITE 70->36.9 MB = ideal).

typedef __bf16 bf16_t;
typedef __bf16 bf16x4 __attribute__((ext_vector_type(4)));
typedef __bf16 bf16x8 __attribute__((ext_vector_type(8)));
typedef float f32x4 __attribute__((ext_vector_type(4)));

#define AS1 __attribute__((address_space(1)))
#define AS3 __attribute__((address_space(3)))

__device__ __forceinline__ void async_ld16(const void* g, void* l) {
  // global -> LDS DMA, 16B/lane; LDS dest is wave-uniform base + lane*16 by HW rule.
  __builtin_amdgcn_global_load_lds((AS1 void*)g, (AS3 void*)l, 16, 0, 0);
}

// 256x256 tile, BK=64, 8 waves (2M x 4N), per-wave 128x64 output = acc[8][4].
// LDS: 2 bufs x (As 256x64 | Bs 256x64) bf16 = 128 KiB (dynamic). 1 block/CU.
// MODE 0: QKV epilogue (bias; Q scaled 1/32; V transposed via LDS).
// MODE 1: S epilogue: store exp(acc) bf16 ldc=4096, atomicAdd fp32 row sums.
// MODE 2: O epilogue: zz<3 -> bf16 partial; zz==3 -> fp32 to fout (1/rowsum).
template <int MODE>
__global__ __launch_bounds__(512, 2) void gemm8(
    const bf16_t* __restrict__ A, const bf16_t* __restrict__ B, const int ld,
    const int Klen, bf16_t* __restrict__ o0, bf16_t* __restrict__ o1,
    bf16_t* __restrict__ o2, const float* __restrict__ b0,
    const float* __restrict__ b1, const float* __restrict__ b2,
    float* __restrict__ fout, float* __restrict__ rowsum) {
  extern __shared__ bf16_t smem[];  // 131072 B

  const int t = threadIdx.x;
  const int lane = t & 63;
  const int wave = t >> 6;
  const int wm = wave >> 2;   // 0..1  (M half)
  const int wn = wave & 3;    // 0..3  (N quarter)
  const int q = lane >> 4;
  const int l16 = lane & 15;
  const int xf = l16 & 7;

  // Grid decode: XCD-aware (bid&7 = XCD), bijective per mode.
  int m0, n0, k0 = 0, zz = 0;
  const int bid = blockIdx.x;
  if constexpr (MODE == 0) {
    // 192 blocks = 16m x 12n; per XCD: 4m x 6n region.
    const int x = bid & 7, sl = bid >> 3;  // sl 0..23
    m0 = ((x >> 1) * 4 + (sl & 3)) * 256;
    n0 = ((x & 1) * 6 + (sl >> 2)) * 256;
  } else if constexpr (MODE == 1) {
    // 256 blocks = 16m x 16n; per XCD: 8m x 4n region.
    const int x = bid & 7, sl = bid >> 3;  // sl 0..31
    m0 = ((x >> 2) * 8 + (sl >> 2)) * 256;
    n0 = ((x & 3) * 4 + (sl & 3)) * 256;
  } else {
    // 256 blocks: split-K z = xcd>>1; per XCD: 8m x 4n of one split.
    const int x = bid & 7, sl = bid >> 3;
    zz = x >> 1;
    m0 = ((x & 1) * 8 + (sl >> 2)) * 256;
    n0 = (sl & 3) * 256;
    k0 = zz * Klen;
  }

  // Staging swizzle (R5-proven, conflict-free): GLOBAL chunk = slot ^ (srow&7);
  // LDS stays linear (HW rule). One quarter (64 rows x 64 k) = 1 load/thread.
  const int srow = t >> 3;                      // 0..63
  const int c8s = ((t & 7) ^ (srow & 7)) * 8;
  const bf16_t* Ab = A + (size_t)(m0 + srow) * ld + k0 + c8s;
  const bf16_t* Bb = B + (size_t)(n0 + srow) * ld + k0 + c8s;
  const int tl8 = t * 8;

  // Read-side: frag (im,s) at row wm*128+im*16+l16, LDS slot ((s*4+q)^xf).
  const int aoff = (wm * 128 + l16) * 64;
  const int boff = (wn * 64 + l16) * 64;
  const int c0 = (q ^ xf) * 8;
  const int c1 = ((4 + q) ^ xf) * 8;

  f32x4 acc[8][4];
  const f32x4 zero4 = {0.f, 0.f, 0.f, 0.f};
#pragma unroll
  for (int i = 0; i < 8; ++i)
#pragma unroll
    for (int j = 0; j < 4; ++j) acc[i][j] = zero4;

  const int NT = Klen >> 6;
  bf16_t* buf0 = smem;          // As(16384 elems) | Bs(16384 elems)
  bf16_t* buf1 = smem + 32768;

  // Burst-stage one full tile (8 DMAs back-to-back: deep vmem queue).
  auto STAGE = [&](int T, bf16_t* buf) {
    const size_t kk = (size_t)(T << 6);
    async_ld16(Ab + kk, buf + tl8);
    async_ld16(Ab + (size_t)64 * ld + kk, buf + 4096 + tl8);
    async_ld16(Ab + (size_t)128 * ld + kk, buf + 8192 + tl8);
    async_ld16(Ab + (size_t)192 * ld + kk, buf + 12288 + tl8);
    async_ld16(Bb + kk, buf + 16384 + tl8);
    async_ld16(Bb + (size_t)64 * ld + kk, buf + 16384 + 4096 + tl8);
    async_ld16(Bb + (size_t)128 * ld + kk, buf + 16384 + 8192 + tl8);
    async_ld16(Bb + (size_t)192 * ld + kk, buf + 16384 + 12288 + tl8);
  };

  STAGE(0, buf0);
  __syncthreads();  // vmcnt(0)+barrier: tile0 resident

  for (int T = 0; T < NT; ++T) {
    bf16_t* cur = (T & 1) ? buf1 : buf0;
    bf16_t* nxt = (T & 1) ? buf0 : buf1;
    if (T + 1 < NT) STAGE(T + 1, nxt);  // in flight across the whole compute

#pragma unroll
    for (int s = 0; s < 2; ++s) {
      const int cs = (s == 0) ? c0 : c1;
      bf16x8 fa[8], fb[4];
#pragma unroll
      for (int im = 0; im < 8; ++im)
        fa[im] = *(const bf16x8*)(cur + aoff + im * 1024 + cs);
#pragma unroll
      for (int j = 0; j < 4; ++j)
        fb[j] = *(const bf16x8*)(cur + 16384 + boff + j * 1024 + cs);
#pragma unroll
      for (int im = 0; im < 8; ++im)
#pragma unroll
        for (int j = 0; j < 4; ++j)
          acc[im][j] = __builtin_amdgcn_mfma_f32_16x16x32_bf16(
              fa[im], fb[j], acc[im][j], 0, 0, 0);
    }
    __syncthreads();  // drains T+1 stage (had full compute phase) + ds_reads
  }

  // C/D layout: col = lane&15, row = quad*4 + reg (m89/m91-verified).
  const int mW = m0 + wm * 128 + q * 4;  // + im*16 + r

  if constexpr (MODE == 0) {
    const int sel = n0 >> 10;  // 0=Q 1=K 2=V  (256-tiles never straddle)
    const int nl0 = (n0 & 1023) + wn * 64 + l16;
    if (sel < 2) {
      const float* bias = (sel == 0) ? b0 : b1;
      const float sc = (sel == 0) ? 0.03125f : 1.0f;  // 1/sqrt(1024) in Q
      bf16_t* dst = (sel == 0) ? o0 : o1;
      float bb[4];
#pragma unroll
      for (int j = 0; j < 4; ++j) bb[j] = bias[nl0 + j * 16];
      // j INNERMOST: 4 consecutive stores complete each 128B run (R13 fix).
#pragma unroll
      for (int im = 0; im < 8; ++im) {
        const int mr = mW + im * 16;
#pragma unroll
        for (int r = 0; r < 4; ++r)
#pragma unroll
          for (int j = 0; j < 4; ++j)
            dst[(size_t)(mr + r) * 1024 + nl0 + j * 16] =
                (bf16_t)((acc[im][j][r] + bb[j]) * sc);
      }
    } else {
      // V^T via LDS transpose (R11-proven, scaled): two passes of 128 d-rows x
      // 256 m; stride 264 elems keeps the free 2-lanes/bank write pattern and
      // a 16B-aligned, 512B-contiguous drain (full-line stores).
      bf16_t* vs = smem;  // 128*264*2 = 67584 B (K-loop buffers dead)
      const int dg0 = n0 & 1023;
#pragma unroll
      for (int h = 0; h < 2; ++h) {
        if ((wn >> 1) == h) {
#pragma unroll
          for (int j = 0; j < 4; ++j) {
            const int dl = (wn & 1) * 64 + j * 16 + l16;  // 0..127
            const float bb = b2[dg0 + h * 128 + dl];
#pragma unroll
            for (int im = 0; im < 8; ++im) {
              bf16x4 v;
#pragma unroll
              for (int r = 0; r < 4; ++r) v[r] = (bf16_t)(acc[im][j][r] + bb);
              *(bf16x4*)(vs + dl * 264 + wm * 128 + im * 16 + q * 4) = v;
            }
          }
        }
        __syncthreads();
#pragma unroll
        for (int rr = 0; rr < 8; ++rr) {
          const int task = rr * 512 + t;
          const int row = task >> 5, ck = task & 31;
          *(bf16x8*)(o2 + (size_t)(dg0 + h * 128 + row) * 4096 + m0 + ck * 8) =
              *(const bf16x8*)(vs + row * 264 + ck * 8);
        }
        __syncthreads();
      }
    }
  } else if constexpr (MODE == 1) {
    float ps[8][4];
#pragma unroll
    for (int im = 0; im < 8; ++im)
#pragma unroll
      for (int r = 0; r < 4; ++r) ps[im][r] = 0.f;
    const int nb = n0 + wn * 64 + l16;
    // j INNERMOST: complete 128B runs back-to-back (R13 write-combine fix).
#pragma unroll
    for (int im = 0; im < 8; ++im) {
      const int mr = mW + im * 16;
#pragma unroll
      for (int r = 0; r < 4; ++r)
#pragma unroll
        for (int j = 0; j < 4; ++j) {
          const float e = __expf(acc[im][j][r]);
          ps[im][r] += e;
          o0[(size_t)(mr + r) * 4096 + nb + j * 16] = (bf16_t)e;
        }
    }
#pragma unroll
    for (int im = 0; im < 8; ++im)
#pragma unroll
      for (int r = 0; r < 4; ++r) {
        float v = ps[im][r];
        v += __shfl_xor(v, 1);
        v += __shfl_xor(v, 2);
        v += __shfl_xor(v, 4);
        v += __shfl_xor(v, 8);
        ps[im][r] = v;
      }
    if (l16 == 0) {
#pragma unroll
      for (int im = 0; im < 8; ++im)
#pragma unroll
        for (int r = 0; r < 4; ++r)
          atomicAdd(rowsum + mW + im * 16 + r, ps[im][r]);
    }
  } else {
    float inv[8][4];
#pragma unroll
    for (int im = 0; im < 8; ++im)
#pragma unroll
      for (int r = 0; r < 4; ++r)
        inv[im][r] = 1.0f / rowsum[mW + im * 16 + r];
    const int nb = n0 + wn * 64 + l16;
    if (zz < 3) {  // bf16 partial (normalized); partials over splits sum to O
      bf16_t* pp = (zz == 0) ? o0 : ((zz == 1) ? o1 : o2);
#pragma unroll
      for (int im = 0; im < 8; ++im) {
        const int mr = mW + im * 16;
#pragma unroll
        for (int r = 0; r < 4; ++r) {
          const float iv = inv[im][r];
#pragma unroll
          for (int j = 0; j < 4; ++j)
            pp[(size_t)(mr + r) * 1024 + nb + j * 16] =
                (bf16_t)(acc[im][j][r] * iv);
        }
      }
    } else {  // zz==3: fp32 partial straight into d_out; reduce adds the rest
#pragma unroll
      for (int im = 0; im < 8; ++im) {
        const int mr = mW + im * 16;
#pragma unroll
        for (int r = 0; r < 4; ++r) {
          const float iv = inv[im][r];
#pragma unroll
          for (int j = 0; j < 4; ++j)
            fout[(size_t)(mr + r) * 1024 + nb + j * 16] = acc[im][j][r] * iv;
        }
      }
    }
  }
}

// Converts X|Wq|Wk|Wv to bf16; last 16 blocks zero rowsum (4096 f32).
__global__ __launch_bounds__(256) void cvt_all(
    const float* __restrict__ X, const float* __restrict__ Wq,
    const float* __restrict__ Wk, const float* __restrict__ Wv,
    bf16_t* __restrict__ Xb, bf16_t* __restrict__ Wb,
    float* __restrict__ rowsum) {
  int i = blockIdx.x * 256 + threadIdx.x;
  if (i >= 1835008) {
    rowsum[i - 1835008] = 0.f;
    return;
  }
  const float* src;
  bf16_t* dst;
  int off;
  if (i < 1048576) {
    src = X; dst = Xb; off = i;
  } else {
    const int w = i - 1048576;
    const int sel = w >> 18;
    off = w & 0x3FFFF;
    src = (sel == 0) ? Wq : ((sel == 1) ? Wk : Wv);
    dst = Wb + (size_t)sel * (1024 * 1024);
  }
  const float4 v = ((const float4*)src)[off];
  bf16x4 o;
  o[0] = (bf16_t)v.x; o[1] = (bf16_t)v.y; o[2] = (bf16_t)v.z; o[3] = (bf16_t)v.w;
  ((bf16x4*)dst)[off] = o;
}

// out[i] += f32(p0[i]) + f32(p1[i]) + f32(p2[i]);  8 elems/thread.
__global__ __launch_bounds__(256) void reduce_out(
    const bf16_t* __restrict__ p0, const bf16_t* __restrict__ p1,
    const bf16_t* __restrict__ p2, float* __restrict__ out) {
  const int i = blockIdx.x * 256 + threadIdx.x;
  const bf16x8 a = ((const bf16x8*)p0)[i];
  const bf16x8 b = ((const bf16x8*)p1)[i];
  const bf16x8 c = ((const bf16x8*)p2)[i];
  float4 lo = ((const float4*)out)[2 * i];
  float4 hi = ((const float4*)out)[2 * i + 1];
  lo.x += (float)a[0] + (float)b[0] + (float)c[0];
  lo.y += (float)a[1] + (float)b[1] + (float)c[1];
  lo.z += (float)a[2] + (float)b[2] + (float)c[2];
  lo.w += (float)a[3] + (float)b[3] + (float)c[3];
  hi.x += (float)a[4] + (float)b[4] + (float)c[4];
  hi.y += (float)a[5] + (float)b[5] + (float)c[5];
  hi.z += (float)a[6] + (float)b[6] + (float)c[6];
  hi.w += (float)a[7] + (float)b[7] + (float)c[7];
  ((float4*)out)[2 * i] = lo;
  ((float4*)out)[2 * i + 1] = hi;
}

extern "C" void kernel_launch(void* const* d_in, const int* in_sizes, int n_in,
                              void* d_out, int out_size, void* d_ws,
                              size_t ws_size, hipStream_t stream) {
  const int S = 4096, D = 1024;
  const float* X  = (const float*)d_in[0];
  const float* Wq = (const float*)d_in[1];
  const float* bq = (const float*)d_in[2];
  const float* Wk = (const float*)d_in[3];
  const float* bk = (const float*)d_in[4];
  const float* Wv = (const float*)d_in[5];
  const float* bv = (const float*)d_in[6];
  float* out = (float*)d_out;

  // ws layout (70 MB bf16 + 16 KB fp32). G3 split-K=4 partials reuse dead
  // regions: Xb (dead after G1), Qb, Kb (dead after G2); z=3 goes to d_out.
  bf16_t* Xb = (bf16_t*)d_ws;            // [4096][1024]
  bf16_t* Wb = Xb + (size_t)S * D;       // [3072][1024]
  bf16_t* Qb = Wb + (size_t)3 * D * D;   // [4096][1024], pre-scaled by 1/32
  bf16_t* Kb = Qb + (size_t)S * D;       // [4096][1024]
  bf16_t* Vt = Kb + (size_t)S * D;       // [1024][4096]  V transposed
  bf16_t* Sc = Vt + (size_t)D * S;       // [4096][4096]  exp(scores)
  float* rowsum = (float*)(Sc + (size_t)S * S);  // [4096]

  // 128 KiB dynamic LDS opt-in (idempotent; not a stream op -> capture-safe).
  static int attr_set = 0;
  if (!attr_set) {
    attr_set = 1;
    (void)hipFuncSetAttribute(reinterpret_cast<const void*>(gemm8<0>),
                              hipFuncAttributeMaxDynamicSharedMemorySize,
                              131072);
    (void)hipFuncSetAttribute(reinterpret_cast<const void*>(gemm8<1>),
                              hipFuncAttributeMaxDynamicSharedMemorySize,
                              131072);
    (void)hipFuncSetAttribute(reinterpret_cast<const void*>(gemm8<2>),
                              hipFuncAttributeMaxDynamicSharedMemorySize,
                              131072);
  }

  cvt_all<<<7184, 256, 0, stream>>>(X, Wq, Wk, Wv, Xb, Wb, rowsum);

  // G1: QKV = Xb @ Wb^T + bias  (M=4096, N=3072, K=1024), 192 blocks
  gemm8<0><<<192, 512, 131072, stream>>>(
      Xb, Wb, D, D, Qb, Kb, Vt, bq, bk, bv, nullptr, nullptr);
  // G2: Sc = exp(Qb @ Kb^T), rowsum partials  (M=N=4096, K=1024), 256 blocks
  gemm8<1><<<256, 512, 131072, stream>>>(
      Qb, Kb, D, D, Sc, nullptr, nullptr, nullptr, nullptr, nullptr, nullptr,
      rowsum);
  // G3: O-partials = (Sc @ Vt^T)/rowsum, K split 4x1024, 256 blocks
  gemm8<2><<<256, 512, 131072, stream>>>(
      Sc, Vt, S, S / 4, Xb, Qb, Kb, nullptr, nullptr, nullptr, out, rowsum);
  // out += p0 + p1 + p2
  reduce_out<<<S * D / 8 / 256, 256, 0, stream>>>(Xb, Qb, Kb, out);
}